// Round 1
// baseline (1458.070 us; speedup 1.0000x reference)
//
#include <hip/hip_runtime.h>

// ---------------------------------------------------------------------------
// GCNModelWPathways: 3-layer GCN (N nodes, BS=8 batch, H=64) + committee
// pathway pooling + 2-layer MLP head + log_softmax.
//
// Decomposition:
//   1. degree count + CSR build (by dst) + dinv = rsqrt(deg+1)
//   2. per layer: linear (wave-per-(n,b), lane=h) then pull-aggregate
//      (block-per-node, thread=(b,h)), fused ReLU+bias and fused fc_w
//      projection into q[N,BS] (mean/linear commute).
//   3. pathway scatter: s_sum[c,b] += q[row[r],b] (atomics, tiny dst buffer)
//   4. head: per-b MLP 400->200->2 + log_softmax.
// ---------------------------------------------------------------------------

__global__ void count_kernel(const int* __restrict__ dst, int* __restrict__ degi, int E) {
  int e = blockIdx.x * blockDim.x + threadIdx.x;
  if (e < E) atomicAdd(&degi[dst[e]], 1);
}

// single-block exclusive prefix sum over counts[0..n) -> row_start[0..n]
__global__ void prefix_kernel(const int* __restrict__ counts, int* __restrict__ row_start, int n) {
  __shared__ int sums[1024];
  int t = threadIdx.x;
  int chunk = (n + 1023) >> 10;
  int beg = t * chunk;
  int end = min(beg + chunk, n);
  int s = 0;
  for (int i = beg; i < end; ++i) s += counts[i];
  sums[t] = s;
  __syncthreads();
  for (int d = 1; d < 1024; d <<= 1) {
    int v = (t >= d) ? sums[t - d] : 0;
    __syncthreads();
    sums[t] += v;
    __syncthreads();
  }
  int off = (t == 0) ? 0 : sums[t - 1];
  for (int i = beg; i < end; ++i) { row_start[i] = off; off += counts[i]; }
  if (end == n) row_start[n] = off;  // all such threads write the total
}

__global__ void fill_kernel(const int* __restrict__ src, const int* __restrict__ dst,
                            const int* __restrict__ row_start, int* __restrict__ cursor,
                            int* __restrict__ csr, int E) {
  int e = blockIdx.x * blockDim.x + threadIdx.x;
  if (e < E) {
    int d = dst[e];
    int pos = atomicAdd(&cursor[d], 1);
    csr[row_start[d] + pos] = src[e];
  }
}

__global__ void dinv_kernel(const int* __restrict__ degi, float* __restrict__ dinv, int N) {
  int n = blockIdx.x * blockDim.x + threadIdx.x;
  if (n < N) dinv[n] = rsqrtf((float)(degi[n] + 1));  // +1: self-loop
}

// m[n,b,h] = sum_f hin[n,b,f] * W[h,f]; wave per (n,b), lane = h.
// FROM_X: hin is x with layout [BS, N, F] (transpose folded into indexing).
template <bool FROM_X>
__global__ void linear_kernel(const float* __restrict__ hin, const float* __restrict__ W,
                              float* __restrict__ m, int N, int BS) {
  __shared__ float Wt[64 * 64];  // Wt[f][h] = W[h][f]; lane-consecutive reads
  int t = threadIdx.x;           // 256 threads = 4 waves
  for (int i = t; i < 64 * 64; i += 256) {
    int h = i >> 6, f = i & 63;
    Wt[f * 64 + h] = W[i];
  }
  __syncthreads();
  int lane = t & 63;
  int idx = blockIdx.x * 4 + (t >> 6);  // (n,b) pair
  if (idx >= N * BS) return;
  int n = idx / BS, b = idx - n * BS;
  float hval = FROM_X ? hin[(b * N + n) * 64 + lane] : hin[idx * 64 + lane];
  float acc = 0.f;
#pragma unroll
  for (int f = 0; f < 64; ++f) {
    float hv = __shfl(hval, f);
    acc = fmaf(hv, Wt[f * 64 + lane], acc);
  }
  m[idx * 64 + lane] = acc;
}

// Pull aggregation: block per dst node n, threads = (b,h) = BS*64.
// acc = self-loop + sum_{incoming e} m[src_e]*dinv[src]*dinv[n]
// val = relu(acc + bias); hout = val; q[n,b] (+)= sum_h val*fcw[h*L+layer]
__global__ void agg_kernel(const float* __restrict__ m, const float* __restrict__ dinv,
                           const float* __restrict__ bias, const int* __restrict__ row_start,
                           const int* __restrict__ csr, float* __restrict__ hout,
                           float* __restrict__ q, const float* __restrict__ fcw,
                           int layer, int L, int BS) {
  int n = blockIdx.x;
  int t = threadIdx.x;  // BS*64
  int b = t >> 6, lane = t & 63;
  float dn = dinv[n];
  int base = n * BS * 64;
  float acc = m[base + t] * (dn * dn);  // self-loop
  int beg = row_start[n], end = row_start[n + 1];
  for (int i = beg; i < end; ++i) {
    int s = csr[i];
    float w = dinv[s] * dn;
    acc = fmaf(m[s * BS * 64 + t], w, acc);
  }
  float val = fmaxf(acc + bias[lane], 0.f);
  hout[base + t] = val;
  float qp = val * fcw[lane * L + layer];
#pragma unroll
  for (int o = 32; o > 0; o >>= 1) qp += __shfl_down(qp, o);
  if (lane == 0) {
    if (layer == 0) q[n * BS + b] = qp;
    else q[n * BS + b] += qp;
  }
}

__global__ void pathway_kernel(const int* __restrict__ row, const int* __restrict__ col,
                               const float* __restrict__ q, float* __restrict__ s_sum,
                               float* __restrict__ cntc, int R, int BS) {
  int idx = blockIdx.x * blockDim.x + threadIdx.x;
  if (idx >= R * BS) return;
  int r = idx / BS, b = idx - (idx / BS) * BS;
  int c = col[r], nd = row[r];
  atomicAdd(&s_sum[c * BS + b], q[nd * BS + b]);
  if (b == 0) atomicAdd(&cntc[c], 1.0f);
}

__global__ void head_kernel(const float* __restrict__ s_sum, const float* __restrict__ cntc,
                            const float* __restrict__ fcb, const float* __restrict__ l1w,
                            const float* __restrict__ l1b, const float* __restrict__ l2w,
                            const float* __restrict__ l2b, float* __restrict__ out,
                            int NCMT, int HFC, int NCLS, int BS) {
  int b = blockIdx.x;
  __shared__ float sbuf[400];
  __shared__ float z1[200];
  __shared__ float z2[8];
  int t = threadIdx.x;  // 256
  for (int c = t; c < NCMT; c += 256) {
    float cn = fmaxf(cntc[c], 1.0f);
    sbuf[c] = s_sum[c * BS + b] / cn + fcb[0];
  }
  __syncthreads();
  for (int j = t; j < HFC; j += 256) {
    float a = l1b[j];
    for (int c = 0; c < NCMT; ++c) a = fmaf(sbuf[c], l1w[j * NCMT + c], a);
    z1[j] = fmaxf(a, 0.f);
  }
  __syncthreads();
  if (t < NCLS) {
    float a = l2b[t];
    for (int j = 0; j < HFC; ++j) a = fmaf(z1[j], l2w[t * HFC + j], a);
    z2[t] = a;
  }
  __syncthreads();
  if (t == 0) {
    float mx = z2[0];
    for (int k = 1; k < NCLS; ++k) mx = fmaxf(mx, z2[k]);
    float se = 0.f;
    for (int k = 0; k < NCLS; ++k) se += expf(z2[k] - mx);
    float lse = mx + logf(se);
    for (int k = 0; k < NCLS; ++k) out[b * NCLS + k] = z2[k] - lse;
  }
}

extern "C" void kernel_launch(void* const* d_in, const int* in_sizes, int n_in,
                              void* d_out, int out_size, void* d_ws, size_t ws_size,
                              hipStream_t stream) {
  const float* x   = (const float*)d_in[0];
  const int*  ei   = (const int*)d_in[2];
  const int*  row  = (const int*)d_in[3];
  const int*  col  = (const int*)d_in[4];
  const float* W1  = (const float*)d_in[5];
  const float* b1  = (const float*)d_in[6];
  const float* W2  = (const float*)d_in[7];
  const float* b2  = (const float*)d_in[8];
  const float* W3  = (const float*)d_in[9];
  const float* b3  = (const float*)d_in[10];
  const float* fcw = (const float*)d_in[11];
  const float* fcb = (const float*)d_in[12];
  const float* l1w = (const float*)d_in[13];
  const float* l1b = (const float*)d_in[14];
  const float* l2w = (const float*)d_in[15];
  const float* l2b = (const float*)d_in[16];

  const int BS   = in_sizes[1];               // 8
  const int H    = in_sizes[6];               // 64
  const int F    = in_sizes[5] / H;           // 64
  const int N    = in_sizes[0] / (BS * F);    // 15135
  const int E    = in_sizes[2] / 2;           // 300000
  const int R    = in_sizes[3];               // 40000
  const int HFC  = in_sizes[14];              // 200
  const int NCMT = in_sizes[13] / HFC;        // 400
  const int NCLS = in_sizes[16];              // 2
  const int L    = in_sizes[11] / H;          // 3

  // workspace carve-out (256B aligned)
  char* p = (char*)d_ws;
  auto alloc = [&](size_t bytes) {
    void* r = (void*)p;
    p += (bytes + 255) & ~(size_t)255;
    return r;
  };
  int*   degi      = (int*)alloc((size_t)N * 4);
  int*   cursor    = (int*)alloc((size_t)N * 4);
  int*   row_start = (int*)alloc((size_t)(N + 1) * 4);
  int*   csr       = (int*)alloc((size_t)E * 4);
  float* dinv      = (float*)alloc((size_t)N * 4);
  float* q         = (float*)alloc((size_t)N * BS * 4);
  float* s_sum     = (float*)alloc((size_t)NCMT * BS * 4);
  float* cntc      = (float*)alloc((size_t)NCMT * 4);
  float* m         = (float*)alloc((size_t)N * BS * H * 4);
  float* hA        = (float*)alloc((size_t)N * BS * H * 4);
  float* hB        = (float*)alloc((size_t)N * BS * H * 4);

  hipMemsetAsync(degi, 0, (size_t)N * 4, stream);
  hipMemsetAsync(cursor, 0, (size_t)N * 4, stream);
  hipMemsetAsync(s_sum, 0, (size_t)NCMT * BS * 4, stream);
  hipMemsetAsync(cntc, 0, (size_t)NCMT * 4, stream);

  const int* e_src = ei;
  const int* e_dst = ei + E;

  count_kernel<<<(E + 255) / 256, 256, 0, stream>>>(e_dst, degi, E);
  prefix_kernel<<<1, 1024, 0, stream>>>(degi, row_start, N);
  fill_kernel<<<(E + 255) / 256, 256, 0, stream>>>(e_src, e_dst, row_start, cursor, csr, E);
  dinv_kernel<<<(N + 255) / 256, 256, 0, stream>>>(degi, dinv, N);

  int lin_grid = (N * BS + 3) / 4;
  int agg_threads = BS * 64;  // 512

  // layer 1 (reads x via transposed indexing)
  linear_kernel<true><<<lin_grid, 256, 0, stream>>>(x, W1, m, N, BS);
  agg_kernel<<<N, agg_threads, 0, stream>>>(m, dinv, b1, row_start, csr, hA, q, fcw, 0, L, BS);
  // layer 2
  linear_kernel<false><<<lin_grid, 256, 0, stream>>>(hA, W2, m, N, BS);
  agg_kernel<<<N, agg_threads, 0, stream>>>(m, dinv, b2, row_start, csr, hB, q, fcw, 1, L, BS);
  // layer 3 (hA is dead, reuse it)
  linear_kernel<false><<<lin_grid, 256, 0, stream>>>(hB, W3, m, N, BS);
  agg_kernel<<<N, agg_threads, 0, stream>>>(m, dinv, b3, row_start, csr, hA, q, fcw, 2, L, BS);

  pathway_kernel<<<((size_t)R * BS + 255) / 256, 256, 0, stream>>>(row, col, q, s_sum, cntc, R, BS);
  head_kernel<<<BS, 256, 0, stream>>>(s_sum, cntc, fcb, l1w, l1b, l2w, l2b,
                                      (float*)d_out, NCMT, HFC, NCLS, BS);
}